// Round 8
// baseline (227.763 us; speedup 1.0000x reference)
//
#include <hip/hip_runtime.h>
#include <hip/hip_fp16.h>

#define WIDTH   640
#define HEIGHT  384
#define PLANE   (WIDTH*HEIGHT)
#define STRIP_H 48
#define NSTRIP  8                 /* 384/48 */
#define GROUPS  24                /* STRIP_H/2 */
#define NBLK    (96*NSTRIP)       /* 768 = 3 blocks/CU exactly */
#define CS_W    656               /* slots 0..649 used, slot = x+5 */
#define SSIM_C1 1.0e-4f
#define SSIM_C2 9.0e-4f
#define INV_N   (1.0f/23592960.0f)

__device__ __forceinline__ __half2 packh2(float a, float b) {
    // single v_cvt_pkrtz_f16_f32; rtz quantization is consistent add/sub so no drift
    __fp16 __attribute__((ext_vector_type(2))) v = __builtin_amdgcn_cvt_pkrtz(a, b);
    __half2 r;
    __builtin_memcpy(&r, &v, sizeof(r));
    return r;
}
__device__ __forceinline__ float2 f2add(float2 a, float2 b) {
    return make_float2(a.x + b.x, a.y + b.y);
}
__device__ __forceinline__ float2 f2sub(float2 a, float2 b) {
    return make_float2(a.x - b.x, a.y - b.y);
}

// Round-7 structure + deferred-eval software pipeline: group g's SSIM math
// (register-only, VALU-chain-heavy) executes during group g+1's Phase A
// (LDS/latency-heavy) -- same scheduling region, no barrier between -> the
// per-wave dependency stalls that capped VALUBusy at ~47% get filled.
// Window regs (a[15],b[15] = 60 VGPR) are held across the barrier; single
// register set, statically indexed (round-2/4 scratch lesson respected).
__global__ __launch_bounds__(256, 3)
void ssim_main(const float* __restrict__ pred, const float* __restrict__ targ,
               float* __restrict__ ws)
{
    __shared__ __half2 ring[11][WIDTH];   // raw (p,t) fp16 pairs, 28.2 KB
    __shared__ float2  csA[2][CS_W];      // {Sp, St}        10.5 KB
    __shared__ float2  csB[2][CS_W];      // {Spp+Stt, Spt}  10.5 KB
    __shared__ float   red[4];

    const int tid   = threadIdx.x;
    const int plane = blockIdx.x % 96;      // vertical neighbors differ by 96 -> same XCD
    const int strip = blockIdx.x / 96;      // 0..7
    const int y0s   = strip * STRIP_H;
    const float* __restrict__ P = pred + plane * PLANE;
    const float* __restrict__ T = targ + plane * PLANE;

    // zero horizontal-halo cs slots once (Phase A never touches them; first
    // Phase-B read is after the first barrier, which orders this write)
    if (tid < 20) {
        int k = tid / 10, j = tid % 10;
        int s = (j < 5) ? j : (640 + j);    // {0..4, 645..649}
        csA[k][s] = make_float2(0.f, 0.f);
        csB[k][s] = make_float2(0.f, 0.f);
    }

    // ---- Bootstrap: stage rows [y0s-6, y0s+4] into ring, build column sums
    //      for output row y0s-1 (all arithmetic on the quantized fp16 values)
    float2 S01[3], S23[3];
#pragma unroll
    for (int c = 0; c < 3; ++c) {
        S01[c] = make_float2(0.f, 0.f);
        S23[c] = make_float2(0.f, 0.f);
    }

#pragma unroll
    for (int c = 0; c < 3; ++c) {
        int x = tid + (c << 8);
        if (x < WIDTH) {
            for (int j = 0; j < 11; ++j) {
                int yy = y0s - 6 + j;
                __half2 h = (yy >= 0) ? packh2(P[yy*WIDTH+x], T[yy*WIDTH+x])
                                      : packh2(0.f, 0.f);
                ring[j][x] = h;
                float2 v = __half22float2(h);
                S01[c] = f2add(S01[c], v);
                S23[c] = f2add(S23[c], make_float2(v.x*v.x + v.y*v.y, v.x*v.y));
            }
        }
    }

    // prefetch registers for the two rows entering the window each group
    float pfP[3][2], pfT[3][2];
    auto do_prefetch = [&](int gg) {
        const int y0 = y0s + (gg << 1);
#pragma unroll
        for (int k = 0; k < 2; ++k) {
            int yn = y0 + k + 5;
            if (yn < HEIGHT) {              // uniform -> scalar branch
#pragma unroll
                for (int c = 0; c < 3; ++c) {
                    int x = tid + (c << 8);
                    if (x < WIDTH) {
                        pfP[c][k] = P[yn*WIDTH + x];
                        pfT[c][k] = T[yn*WIDTH + x];
                    }
                }
            } else {
#pragma unroll
                for (int c = 0; c < 3; ++c) { pfP[c][k] = 0.f; pfT[c][k] = 0.f; }
            }
        }
    };
    do_prefetch(0);

    float acc = 0.f;
    const float inv121 = 1.0f / 121.0f;
    const int r    = tid >> 6;
    const int lane = tid & 63;
    const int kb   = r & 1;
    const int base = ((r >> 1) * 320) + lane * 5;   // slots [base, base+14]
    int rs = 0;   // ring slot of the row leaving/entering at k=0 of this group

    float  cP[3][2], cT[3][2];
    float2 a[15], b[15];      // held window of column sums (60 VGPRs)

    auto consume_and_prefetch = [&](int gnext) {
#pragma unroll
        for (int c = 0; c < 3; ++c)
#pragma unroll
            for (int k = 0; k < 2; ++k) { cP[c][k] = pfP[c][k]; cT[c][k] = pfT[c][k]; }
        if (gnext < GROUPS) do_prefetch(gnext);
    };

    // Phase A: advance 2 rows; subtract old from LDS ring, add new;
    // cs writes are ds_write_b64 pairs
    auto phaseA = [&]() {
#pragma unroll
        for (int c = 0; c < 3; ++c) {
            int x = tid + (c << 8);
            if (x < WIDTH) {
#pragma unroll
                for (int k = 0; k < 2; ++k) {
                    int slot = rs + k; if (slot >= 11) slot -= 11;
                    __half2 hn = packh2(cP[c][k], cT[c][k]);
                    __half2 ho = ring[slot][x];
                    ring[slot][x] = hn;
                    float2 nq = __half22float2(hn);   // use quantized value
                    float2 o2 = __half22float2(ho);
                    S01[c] = f2add(S01[c], f2sub(nq, o2));
                    float2 pn = make_float2(nq.x*nq.x + nq.y*nq.y, nq.x*nq.y);
                    float2 po = make_float2(o2.x*o2.x + o2.y*o2.y, o2.x*o2.y);
                    S23[c] = f2add(S23[c], f2sub(pn, po));
                    csA[k][x + 5] = S01[c];
                    csB[k][x + 5] = S23[c];
                }
            }
        }
    };

    // load the 15-slot window into registers (30 ds_read_b64, loop-invariant
    // addresses -> one base VGPR + immediate offsets)
    auto readW = [&]() {
#pragma unroll
        for (int j = 0; j < 15; ++j) {
            a[j] = csA[kb][base + j];
            b[j] = csB[kb][base + j];
        }
    };

    // SSIM math for the held window; tree-reassociated 11-sum (depth 4) so
    // the chain is short enough to interleave with Phase A's stream
    auto evalW = [&]() {
        float2 A  = f2add(f2add(f2add(a[0], a[1]), f2add(a[2], a[3])),
                          f2add(f2add(a[4], a[5]), f2add(a[6], a[7])));
        A  = f2add(A,  f2add(f2add(a[8], a[9]), a[10]));
        float2 Bv = f2add(f2add(f2add(b[0], b[1]), f2add(b[2], b[3])),
                          f2add(f2add(b[4], b[5]), f2add(b[6], b[7])));
        Bv = f2add(Bv, f2add(f2add(b[8], b[9]), b[10]));
#pragma unroll
        for (int i = 0; i < 5; ++i) {
            if (i > 0) {
                A  = f2add(A,  f2sub(a[10 + i], a[i - 1]));
                Bv = f2add(Bv, f2sub(b[10 + i], b[i - 1]));
            }
            float mp  = A.x * inv121, mt = A.y * inv121;
            float mpp = mp*mp, mtt = mt*mt, mpt = mp*mt;
            float s2  = Bv.x * inv121 - mpp - mtt;   // sigma_p + sigma_t
            float spt = Bv.y * inv121 - mpt;         // sigma_pt
            float num = (2.f*mpt + SSIM_C1) * (2.f*spt + SSIM_C2);
            float den = (mpp + mtt + SSIM_C1) * (s2 + SSIM_C2);
            acc += num * __builtin_amdgcn_rcpf(den);
        }
    };

    // ---- group 0 (peeled): A + read, no eval yet
    consume_and_prefetch(1);
    phaseA();
    __syncthreads();
    readW();
    __syncthreads();
    rs = 2;

#pragma clang loop unroll(disable)
    for (int g = 1; g < GROUPS; ++g) {
        consume_and_prefetch(g + 1);
        phaseA();     // group g: LDS-heavy
        evalW();      // group g-1: register-only chain math -- interleaves
        __syncthreads();
        readW();      // group g window -> regs
        __syncthreads();
        rs += 2; if (rs >= 11) rs -= 11;
    }
    evalW();          // last group

    // ---- block reduction -> one plain store per block (no atomics)
#pragma unroll
    for (int off = 32; off >= 1; off >>= 1)
        acc += __shfl_down(acc, off);
    if ((tid & 63) == 0) red[tid >> 6] = acc;
    __syncthreads();
    if (tid == 0)
        ws[blockIdx.x] = red[0] + red[1] + red[2] + red[3];
}

__global__ void ssim_reduce(const float* __restrict__ ws, float* __restrict__ out)
{
    __shared__ float red[4];
    const int tid = threadIdx.x;
    float s = ws[tid] + ws[tid + 256] + ws[tid + 512];
#pragma unroll
    for (int off = 32; off >= 1; off >>= 1)
        s += __shfl_down(s, off);
    if ((tid & 63) == 0) red[tid >> 6] = s;
    __syncthreads();
    if (tid == 0)
        out[0] = 1.0f - (red[0] + red[1] + red[2] + red[3]) * INV_N;
}

extern "C" void kernel_launch(void* const* d_in, const int* in_sizes, int n_in,
                              void* d_out, int out_size, void* d_ws, size_t ws_size,
                              hipStream_t stream) {
    const float* pred = (const float*)d_in[0];
    const float* targ = (const float*)d_in[1];
    float* out = (float*)d_out;
    float* ws  = (float*)d_ws;          // 768 floats of partial sums
    ssim_main<<<NBLK, 256, 0, stream>>>(pred, targ, ws);
    ssim_reduce<<<1, 256, 0, stream>>>(ws, out);
}